// Round 9
// baseline (407.590 us; speedup 1.0000x reference)
//
#include <hip/hip_runtime.h>
#include <hip/hip_bf16.h>

#define N 8192
#define FIN 128
#define FOUT 64
#define ALPHA 0.2f
#define LOG2E 1.44269504f
#define JSPLIT 4
#define JSPAN (N / JSPLIT)    // 2048 j per block
#define STJ 256               // j per stage = 8 units of 32
#define NST (JSPAN / STJ)     // 8 stages
#define RSA 260               // bufA row stride (floats): 1040 B, breaks pow2
#define RSP 264               // pbuf row stride (bf16): 528 B, 16B-aligned rows

typedef __attribute__((ext_vector_type(8))) short short8;
typedef __attribute__((ext_vector_type(4))) float f32x4;

static __device__ __forceinline__ unsigned fkey(float x) {
    unsigned u = __float_as_uint(x);
    return (u >> 31) ? ~u : (u | 0x80000000u);
}
static __device__ __forceinline__ float fdecode(unsigned k) {
    unsigned u = (k & 0x80000000u) ? (k & 0x7FFFFFFFu) : ~k;
    return __uint_as_float(u);
}
// async global->LDS DMA: per-lane 16B; LDS dest = wave-uniform base + lane*16.
static __device__ __forceinline__ void gll16(const float* g, float* l) {
    __builtin_amdgcn_global_load_lds(
        (const __attribute__((address_space(1))) unsigned int*)g,
        (__attribute__((address_space(3))) unsigned int*)l, 16, 0, 0);
}

// ---------------- k_prep: Wh = h@W; s2 = (Wh@a1)*log2e; t2 = (Wh@a2)*log2e --------
__global__ __launch_bounds__(256) void k_prep(const float* __restrict__ h,
                                              const float* __restrict__ W,
                                              const float* __restrict__ a,
                                              float* __restrict__ Wh,
                                              float* __restrict__ s2,
                                              float* __restrict__ t2,
                                              unsigned* __restrict__ keys) {
    __shared__ float lH[16 * FIN];
    __shared__ float lW[FIN * FOUT];
    __shared__ float red[8];
    const int tid = threadIdx.x;
    const int r0 = blockIdx.x * 16;
    {
        const float4* src = (const float4*)(h + (size_t)r0 * FIN);
        float4* dst = (float4*)lH;
        for (int i = tid; i < 16 * FIN / 4; i += 256) dst[i] = src[i];
        const float4* ws_ = (const float4*)W;
        float4* dw = (float4*)lW;
        for (int i = tid; i < FIN * FOUT / 4; i += 256) dw[i] = ws_[i];
    }
    __syncthreads();
    const int wave = tid >> 6, lane = tid & 63;
    float acc[4] = {0.f, 0.f, 0.f, 0.f};
    for (int k = 0; k < FIN; ++k) {
        float wv = lW[k * FOUT + lane];
#pragma unroll
        for (int r = 0; r < 4; ++r)
            acc[r] = fmaf(lH[(wave * 4 + r) * FIN + k], wv, acc[r]);
    }
    const float a1 = a[lane], a2 = a[FOUT + lane];
    float smx = -1e30f, tmx = -1e30f;
#pragma unroll
    for (int r = 0; r < 4; ++r) {
        int row = r0 + wave * 4 + r;
        Wh[(size_t)row * FOUT + lane] = acc[r];
        float sv = acc[r] * a1, tv = acc[r] * a2;
#pragma unroll
        for (int off = 32; off; off >>= 1) {
            sv += __shfl_xor(sv, off);
            tv += __shfl_xor(tv, off);
        }
        sv *= LOG2E; tv *= LOG2E;      // pre-scale: exp(x) -> exp2(x')
        if (lane == 0) { s2[row] = sv; t2[row] = tv; }
        smx = fmaxf(smx, sv);
        tmx = fmaxf(tmx, tv);
    }
    if (lane == 0) { red[wave] = smx; red[4 + wave] = tmx; }
    __syncthreads();
    if (tid == 0) {
        float ms = fmaxf(fmaxf(red[0], red[1]), fmaxf(red[2], red[3]));
        float mt = fmaxf(fmaxf(red[4], red[5]), fmaxf(red[6], red[7]));
        atomicMax(keys + 0, fkey(ms));
        atomicMax(keys + 1, fkey(mt));
    }
}

// ---------------- k_pack: Wh fp32 -> bf16 B-fragment layout ------------------------
// B-frag (16x16x32): lane holds col n = lane&15, k = (lane>>4)*8 + e
__global__ __launch_bounds__(256) void k_pack(const float* __restrict__ Wh,
                                              __hip_bfloat16* __restrict__ WhB) {
    const int c = blockIdx.x;
    const int tn = threadIdx.x >> 6;
    const int lane = threadIdx.x & 63;
    const int quad = lane >> 4, l16 = lane & 15;
    const float* src = Wh + ((size_t)(c * 32 + quad * 8)) * FOUT + tn * 16 + l16;
    union { unsigned short u[8]; short8 v; } frag;
#pragma unroll
    for (int e = 0; e < 8; ++e) {
        __hip_bfloat16 b = __float2bfloat16(src[(size_t)e * FOUT]);
        frag.u[e] = *(unsigned short*)&b;
    }
    *(short8*)&WhB[(((size_t)c * 4 + tn) * 64 + lane) * 8] = frag.v;
}

// ---------------- k_attn: fused mask+softmax+PV, barrier-light K-loop --------------
// Grid (N/16, 4); block 256 = 4 waves owns 16 rows x 2048 j. Stage = 16x256 adj,
// row-major coalesced DMA (1 KB/instr). Wave w DMAs AND p-processes ONLY rows
// 4w..4w+3 -> bufA has no cross-wave hazard -> no vmcnt(0), no __syncthreads in
// the loop. pbuf (bf16 P frags) is the only shared data: raw s_barrier x2.
// B-frags issued first each iter; their auto-wait vmcnt(4) leaves newest DMA flying.
__global__ __launch_bounds__(256) void k_attn(const float* __restrict__ adj,
                                              const __hip_bfloat16* __restrict__ WhB,
                                              const float* __restrict__ s2,
                                              const float* __restrict__ t2,
                                              const unsigned* __restrict__ keys,
                                              float* __restrict__ acc_ws,
                                              float* __restrict__ l_ws) {
    __shared__ float bufA[2][16 * RSA];          // 33280 B; reused as epilogue accr
    __shared__ __hip_bfloat16 pbuf[16 * RSP];    // 8448 B
    __shared__ float tl[JSPAN];                  // 8192 B
    const int wave = threadIdx.x >> 6, lane = threadIdx.x & 63;
    const int quad = lane >> 4, l16 = lane & 15;
    const int i0 = blockIdx.x * 16;
    const int jb = blockIdx.y * JSPAN;
    const int r0 = 4 * wave;                      // this wave's row group

    // t2 slice -> LDS once (out of the vmcnt stream)
    for (int i = threadIdx.x; i < JSPAN / 4; i += 256)
        ((float4*)tl)[i] = ((const float4*)(t2 + jb))[i];
    asm volatile("s_waitcnt lgkmcnt(0)" ::: "memory");
    __builtin_amdgcn_sched_barrier(0);

    // per-row global bases (lane*4 floats = coalesced 1 KB per DMA instr)
    const float* g0 = adj + (size_t)(i0 + r0 + 0) * N + jb + lane * 4;
    const float* g1 = g0 + N;
    const float* g2 = g0 + 2 * N;
    const float* g3 = g0 + 3 * N;

    // prologue: DMA stage 0 -> bufA[0], stage 1 -> bufA[1]
    gll16(g0, &bufA[0][(r0 + 0) * RSA]);
    gll16(g1, &bufA[0][(r0 + 1) * RSA]);
    gll16(g2, &bufA[0][(r0 + 2) * RSA]);
    gll16(g3, &bufA[0][(r0 + 3) * RSA]);
    gll16(g0 + STJ, &bufA[1][(r0 + 0) * RSA]);
    gll16(g1 + STJ, &bufA[1][(r0 + 1) * RSA]);
    gll16(g2 + STJ, &bufA[1][(r0 + 2) * RSA]);
    gll16(g3 + STJ, &bufA[1][(r0 + 3) * RSA]);
    __builtin_amdgcn_sched_barrier(0);
    asm volatile("s_waitcnt vmcnt(4)" ::: "memory");   // own stage-0 rows landed

    const float mraw = fdecode(keys[0]) + fdecode(keys[1]);
    const float mm = mraw > 0.f ? mraw : ALPHA * mraw;
    float sr[4];
#pragma unroll
    for (int rr = 0; rr < 4; ++rr) sr[rr] = s2[i0 + r0 + rr];
    const short8* BF = (const short8*)WhB;

    f32x4 acc0 = {0,0,0,0}, acc1 = {0,0,0,0}, acc2 = {0,0,0,0}, acc3 = {0,0,0,0};
    float ls[4] = {0.f, 0.f, 0.f, 0.f};

    for (int st = 0; st < NST; ++st) {
        const int b = st & 1;
        // [1] B-frags for this wave's units 2w,2w+1 (L2-resident; issued FIRST)
        const size_t kc = ((size_t)blockIdx.y * (JSPAN / 32) + st * 8 + 2 * wave) * 4;
        short8 B00 = BF[(kc + 0) * 64 + lane];
        short8 B01 = BF[(kc + 1) * 64 + lane];
        short8 B02 = BF[(kc + 2) * 64 + lane];
        short8 B03 = BF[(kc + 3) * 64 + lane];
        short8 B10 = BF[(kc + 4) * 64 + lane];
        short8 B11 = BF[(kc + 5) * 64 + lane];
        short8 B12 = BF[(kc + 6) * 64 + lane];
        short8 B13 = BF[(kc + 7) * 64 + lane];
        __builtin_amdgcn_sched_barrier(0);
        // [2] raw barrier: prev iter's pbuf reads done; NO vmcnt drain
        asm volatile("s_barrier" ::: "memory");
        // [3] p-phase on own rows, coalesced lane=j layout; p computed ONCE
        float4 tv = *(const float4*)&tl[st * STJ + lane * 4];
#pragma unroll
        for (int rr = 0; rr < 4; ++rr) {
            float4 av = *(const float4*)&bufA[b][(r0 + rr) * RSA + lane * 4];
            union { __hip_bfloat162 h2[2]; uint2 u2; } pk;
            float lacc = 0.f;
#pragma unroll
            for (int pp = 0; pp < 2; ++pp) {
                float x0 = sr[rr] + ((const float*)&tv)[2 * pp];
                float x1 = sr[rr] + ((const float*)&tv)[2 * pp + 1];
                float le0 = fmaxf(x0, ALPHA * x0), le1 = fmaxf(x1, ALPHA * x1);
                float p0 = ((const float*)&av)[2 * pp] * exp2f(le0 - mm);
                float p1 = ((const float*)&av)[2 * pp + 1] * exp2f(le1 - mm);
                __hip_bfloat162 pb = __float22bfloat162_rn(make_float2(p0, p1));
                pk.h2[pp] = pb;
                lacc += __bfloat162float(pb.x) + __bfloat162float(pb.y);
            }
            *(uint2*)&pbuf[(r0 + rr) * RSP + lane * 4] = pk.u2;
            ls[rr] += lacc;   // denominator from bf16-ROUNDED p (consistent)
        }
        __builtin_amdgcn_sched_barrier(0);
        // [4] DMA stage st+2 into bufA[b] (own rows already read; clamp keeps
        //     vmem counts constant so every wait below is exact)
        const int sd = (st + 2 < NST ? st + 2 : NST - 1) * STJ;
        gll16(g0 + sd, &bufA[b][(r0 + 0) * RSA]);
        gll16(g1 + sd, &bufA[b][(r0 + 1) * RSA]);
        gll16(g2 + sd, &bufA[b][(r0 + 2) * RSA]);
        gll16(g3 + sd, &bufA[b][(r0 + 3) * RSA]);
        __builtin_amdgcn_sched_barrier(0);
        // [5] own pbuf writes visible, then raw barrier (lgkm only — DMA flies on)
        asm volatile("s_waitcnt lgkmcnt(0)" ::: "memory");
        asm volatile("s_barrier" ::: "memory");
        // [6] MFMA: units 2w, 2w+1; B consumption auto-waits vmcnt(4),
        //     leaving the st+2 DMA in flight
#pragma unroll
        for (int uu = 0; uu < 2; ++uu) {
            short8 af = *(const short8*)&pbuf[l16 * RSP + (2 * wave + uu) * 32 + quad * 8];
            if (uu == 0) {
                acc0 = __builtin_amdgcn_mfma_f32_16x16x32_bf16(af, B00, acc0, 0, 0, 0);
                acc1 = __builtin_amdgcn_mfma_f32_16x16x32_bf16(af, B01, acc1, 0, 0, 0);
                acc2 = __builtin_amdgcn_mfma_f32_16x16x32_bf16(af, B02, acc2, 0, 0, 0);
                acc3 = __builtin_amdgcn_mfma_f32_16x16x32_bf16(af, B03, acc3, 0, 0, 0);
            } else {
                acc0 = __builtin_amdgcn_mfma_f32_16x16x32_bf16(af, B10, acc0, 0, 0, 0);
                acc1 = __builtin_amdgcn_mfma_f32_16x16x32_bf16(af, B11, acc1, 0, 0, 0);
                acc2 = __builtin_amdgcn_mfma_f32_16x16x32_bf16(af, B12, acc2, 0, 0, 0);
                acc3 = __builtin_amdgcn_mfma_f32_16x16x32_bf16(af, B13, acc3, 0, 0, 0);
            }
        }
    }
    __syncthreads();  // end of K-loop: full drain is fine here

    // lsum: reduce each row partial across the 64 lanes (lane covered j = lane*4+..)
#pragma unroll
    for (int rr = 0; rr < 4; ++rr) {
        float v = ls[rr];
#pragma unroll
        for (int off = 32; off; off >>= 1) v += __shfl_xor(v, off);
        if (lane == 0) atomicAdd(&l_ws[i0 + r0 + rr], v);
    }

    // epilogue: reuse bufA as accr[4 waves][4 tiles][64 lanes][4]
    float* accr = &bufA[0][0];
    *(f32x4*)&accr[((wave * 4 + 0) * 64 + lane) * 4] = acc0;
    *(f32x4*)&accr[((wave * 4 + 1) * 64 + lane) * 4] = acc1;
    *(f32x4*)&accr[((wave * 4 + 2) * 64 + lane) * 4] = acc2;
    *(f32x4*)&accr[((wave * 4 + 3) * 64 + lane) * 4] = acc3;
    __syncthreads();
    const int tile = wave;
    f32x4 tot = {0, 0, 0, 0};
#pragma unroll
    for (int w = 0; w < 4; ++w) {
        f32x4 c = *(const f32x4*)&accr[((w * 4 + tile) * 64 + lane) * 4];
        tot[0] += c[0]; tot[1] += c[1]; tot[2] += c[2]; tot[3] += c[3];
    }
#pragma unroll
    for (int r = 0; r < 4; ++r) {
        int row = quad * 4 + r;  // C/D: row=(lane>>4)*4+reg, col=l16 within tile
        atomicAdd(&acc_ws[(size_t)(i0 + row) * FOUT + tile * 16 + l16], tot[r]);
    }
}

// ---------------- k_final: out = elu(acc/l) ---------------------------------------
__global__ __launch_bounds__(256) void k_final(const float* __restrict__ acc_ws,
                                               const float* __restrict__ l_ws,
                                               float* __restrict__ out) {
    const int idx = blockIdx.x * 256 + threadIdx.x;   // one float4 per thread
    const int row = idx >> 4;                          // 16 float4 per row
    const float inv = 1.0f / l_ws[row];
    float4 a = ((const float4*)acc_ws)[idx];
    float4 o;
#pragma unroll
    for (int r = 0; r < 4; ++r) {
        float v = ((const float*)&a)[r] * inv;
        ((float*)&o)[r] = v > 0.f ? v : (exp2f(v * LOG2E) - 1.f);
    }
    ((float4*)out)[idx] = o;
}

extern "C" void kernel_launch(void* const* d_in, const int* in_sizes, int n_in,
                              void* d_out, int out_size, void* d_ws, size_t ws_size,
                              hipStream_t stream) {
    const float* h   = (const float*)d_in[0];
    const float* adj = (const float*)d_in[1];
    const float* W   = (const float*)d_in[2];
    const float* a   = (const float*)d_in[3];
    float* out = (float*)d_out;

    char* base = (char*)d_ws;
    float* Wh = (float*)base;                        base += (size_t)N * FOUT * 4;
    __hip_bfloat16* WhB = (__hip_bfloat16*)base;     base += (size_t)N * FOUT * 2;
    float* s2 = (float*)base;                        base += (size_t)N * 4;
    float* t2 = (float*)base;                        base += (size_t)N * 4 + 1024;
    float* acc_ws = (float*)base;                    base += (size_t)N * FOUT * 4;
    float* l_ws = (float*)base;                      base += (size_t)N * 4;
    unsigned* keys = (unsigned*)base;

    hipMemsetAsync(acc_ws, 0, ((size_t)N * FOUT + N) * 4 + 2 * sizeof(unsigned), stream);
    k_prep<<<N / 16, 256, 0, stream>>>(h, W, a, Wh, s2, t2, keys);
    k_pack<<<N / 32, 256, 0, stream>>>(Wh, WhB);
    dim3 ag(N / 16, JSPLIT);
    k_attn<<<ag, 256, 0, stream>>>(adj, WhB, s2, t2, keys, acc_ws, l_ws);
    k_final<<<N * FOUT / 4 / 256, 256, 0, stream>>>(acc_ws, l_ws, out);
}